// Round 3
// baseline (227.466 us; speedup 1.0000x reference)
//
#include <hip/hip_runtime.h>
#include <hip/hip_bf16.h>
#include <math.h>

// Chamfer distance via MFMA (bf16 hi/lo split), B=8, N=M=8192, D=3, fp32.
//   C[m][n] = q_m . r_n - 0.5*||r_n||^2  computed by 3 chained
//   v_mfma_f32_32x32x16_bf16 (AhiBhi + AhiBlo + AloBhi), K=4 of 16 used:
//     A row m: (qx, qy, qz, 1)hi , (qx, qy, qz, 0)lo
//     B col n: (rx, ry, rz, w)hi/lo,  w = -0.5*||r||^2
//   min_j d2 = ||q||^2 - 2 * max_n C   (clamped at 0)
// Dropped lo*lo term ~2^-16 relative; output is a mean over 131k queries so
// the scalar error averages to ~1e-5, far under the 9.3e-4 threshold.

#define BLOCK 256
#define WAVES 4     // waves per block
#define QPW 32      // queries per wave   (MFMA M)
#define TILE_R 32   // refs per tile      (MFMA N)

typedef short short8 __attribute__((ext_vector_type(8)));
typedef float f32x16 __attribute__((ext_vector_type(16)));

union F8 { short8 s; unsigned int u[4]; };

__device__ __forceinline__ unsigned int bf16hi(float f) {
    __hip_bfloat16 h = __float2bfloat16(f);
    return (unsigned int)*reinterpret_cast<unsigned short*>(&h);
}
__device__ __forceinline__ float bf16f(unsigned int u) {
    unsigned short us = (unsigned short)u;
    __hip_bfloat16 h;
    *reinterpret_cast<unsigned short*>(&h) = us;
    return __bfloat162float(h);
}

// Split every point into a 16B record: {xhi,yhi,zhi,whi, xlo,ylo,zlo,wlo} bf16,
// where w = -0.5*||p||^2. Also zero the output scalar.
__global__ void prep_kernel(const float* __restrict__ gts, const float* __restrict__ preds,
                            int nG, int nP, uint4* __restrict__ prepG,
                            uint4* __restrict__ prepP, float* out) {
    const int idx = blockIdx.x * blockDim.x + threadIdx.x;
    if (idx == 0) out[0] = 0.0f;
    if (idx >= nG + nP) return;
    const float* src;
    uint4* dst;
    if (idx < nG) { src = gts + 3 * (size_t)idx;          dst = prepG + idx; }
    else          { src = preds + 3 * (size_t)(idx - nG); dst = prepP + (idx - nG); }
    const float x = src[0], y = src[1], z = src[2];
    const float w = -0.5f * (x * x + y * y + z * z);
    const unsigned int xh = bf16hi(x), yh = bf16hi(y), zh = bf16hi(z), wh = bf16hi(w);
    const unsigned int xl = bf16hi(x - bf16f(xh));
    const unsigned int yl = bf16hi(y - bf16f(yh));
    const unsigned int zl = bf16hi(z - bf16f(zh));
    const unsigned int wl = bf16hi(w - bf16f(wh));
    uint4 rec;
    rec.x = xh | (yh << 16);
    rec.y = zh | (wh << 16);
    rec.z = xl | (yl << 16);
    rec.w = zl | (wl << 16);
    *dst = rec;
}

// blockIdx.z in [0,2B): z<B -> queries=gts, refs=preds (kmaxX); else swapped.
// Each wave owns 32 queries, loops over all ref tiles of 32; per-query max of C
// finished entirely within the wave (no atomics).
__global__ void __launch_bounds__(BLOCK)
nn_kernel(const uint4* __restrict__ prepG, const uint4* __restrict__ prepP,
          float* __restrict__ kmaxX, float* __restrict__ kmaxY,
          int N, int M, int B) {
    const int z = blockIdx.z;
    const bool dirX = (z < B);
    const int b = dirX ? z : z - B;
    const int NQ = dirX ? N : M;
    const int NR = dirX ? M : N;
    const uint4* Q = (dirX ? prepG : prepP) + (size_t)b * NQ;
    const uint4* R = (dirX ? prepP : prepG) + (size_t)b * NR;
    float* outK = (dirX ? kmaxX : kmaxY) + (size_t)b * NQ;

    const int lane = threadIdx.x & 63;
    const int wave = threadIdx.x >> 6;
    const int qBase = (blockIdx.x * WAVES + wave) * QPW;
    if (qBase >= NQ) return;

    // ---- A fragments: lanes 0-31 hold k=0..7 (we use k=0..3); lanes 32-63 zero
    short8 ahi = (short8)0, alo = (short8)0;
    if (lane < 32) {
        const uint4 qr = Q[qBase + lane];
        F8 H, L;
        H.u[0] = qr.x;                                      // (qx, qy) hi
        H.u[1] = (qr.y & 0xFFFFu) | (0x3F80u << 16);        // (qz, 1.0bf16)
        H.u[2] = 0; H.u[3] = 0;
        L.u[0] = qr.z;                                      // (qx, qy) lo
        L.u[1] = qr.w & 0xFFFFu;                            // (qz lo, 0)
        L.u[2] = 0; L.u[3] = 0;
        ahi = H.s; alo = L.s;
    }

    const f32x16 zeroC = (f32x16)0.0f;
    f32x16 kmax = (f32x16)(-INFINITY);

    const int nTiles = NR / TILE_R;
    const uint4* rp = R + (lane & 31);       // lanes 32-63 mirror 0-31 (finite data; A zeros there)
    uint4 rec = rp[0];

    for (int t = 0; t < nTiles; ++t) {
        const int tn = (t + 1 < nTiles) ? (t + 1) : t;
        const uint4 nxt = rp[(size_t)tn * TILE_R];          // prefetch next tile

        F8 BH, BL;
        BH.u[0] = rec.x; BH.u[1] = rec.y; BH.u[2] = 0; BH.u[3] = 0;
        BL.u[0] = rec.z; BL.u[1] = rec.w; BL.u[2] = 0; BL.u[3] = 0;

        f32x16 c = __builtin_amdgcn_mfma_f32_32x32x16_bf16(alo, BH.s, zeroC, 0, 0, 0);
        c = __builtin_amdgcn_mfma_f32_32x32x16_bf16(ahi, BL.s, c, 0, 0, 0);
        c = __builtin_amdgcn_mfma_f32_32x32x16_bf16(ahi, BH.s, c, 0, 0, 0);

        #pragma unroll
        for (int r = 0; r < 16; ++r) kmax[r] = fmaxf(kmax[r], c[r]);

        rec = nxt;
    }

    // ---- cross-lane max over the 32 columns in each half, then store per row.
    // C/D layout: col = lane&31, row = (reg&3) + 8*(reg>>2) + 4*(lane>>5).
    #pragma unroll
    for (int r = 0; r < 16; ++r) {
        float v = kmax[r];
        v = fmaxf(v, __shfl_xor(v, 16));
        v = fmaxf(v, __shfl_xor(v, 8));
        v = fmaxf(v, __shfl_xor(v, 4));
        v = fmaxf(v, __shfl_xor(v, 2));
        v = fmaxf(v, __shfl_xor(v, 1));
        const int row = (r & 3) + 8 * (r >> 2) + 4 * (lane >> 5);
        if ((lane & 31) == 0) outK[qBase + row] = v;
    }
}

// d2_min = max(0, ||q||^2 - 2*kmax); weighted means of both directions.
__global__ void __launch_bounds__(BLOCK)
reduce_kernel(const float* __restrict__ kmaxX, const float* __restrict__ gts, int totalx,
              const float* __restrict__ kmaxY, const float* __restrict__ preds, int totaly,
              float invx, float invy, float* __restrict__ out) {
    const int total = totalx + totaly;
    float local = 0.0f;
    for (int idx = blockIdx.x * blockDim.x + threadIdx.x; idx < total;
         idx += gridDim.x * blockDim.x) {
        if (idx < totalx) {
            const float* p = gts + 3 * (size_t)idx;
            const float x2 = p[0] * p[0] + p[1] * p[1] + p[2] * p[2];
            local += fmaxf(x2 - 2.0f * kmaxX[idx], 0.0f) * invx;
        } else {
            const int j = idx - totalx;
            const float* p = preds + 3 * (size_t)j;
            const float y2 = p[0] * p[0] + p[1] * p[1] + p[2] * p[2];
            local += fmaxf(y2 - 2.0f * kmaxY[j], 0.0f) * invy;
        }
    }
    __shared__ float waveSums[BLOCK / 64];
    float v = local;
    #pragma unroll
    for (int off = 32; off > 0; off >>= 1) v += __shfl_down(v, off, 64);
    const int lane = threadIdx.x & 63;
    const int wv = threadIdx.x >> 6;
    if (lane == 0) waveSums[wv] = v;
    __syncthreads();
    if (threadIdx.x == 0) {
        float s = 0.0f;
        #pragma unroll
        for (int w = 0; w < BLOCK / 64; ++w) s += waveSums[w];
        atomicAdd(out, s);
    }
}

extern "C" void kernel_launch(void* const* d_in, const int* in_sizes, int n_in,
                              void* d_out, int out_size, void* d_ws, size_t ws_size,
                              hipStream_t stream) {
    const float* gts   = (const float*)d_in[0];   // [B, N, 3]
    const float* preds = (const float*)d_in[1];   // [B, M, 3]
    float* out = (float*)d_out;

    const int B = 8;
    const int N = in_sizes[0] / (B * 3);
    const int M = in_sizes[1] / (B * 3);
    const int nG = B * N, nP = B * M;

    uint4* prepG = (uint4*)d_ws;                  // nG * 16 B
    uint4* prepP = prepG + nG;                    // nP * 16 B
    float* kmaxX = (float*)(prepP + nP);          // nG floats
    float* kmaxY = kmaxX + nG;                    // nP floats

    prep_kernel<<<(nG + nP + BLOCK - 1) / BLOCK, BLOCK, 0, stream>>>(
        gts, preds, nG, nP, prepG, prepP, out);

    const int maxQ = (N > M) ? N : M;
    dim3 grid((maxQ + WAVES * QPW - 1) / (WAVES * QPW), 1, 2 * B);
    nn_kernel<<<grid, BLOCK, 0, stream>>>(prepG, prepP, kmaxX, kmaxY, N, M, B);

    const float invx = 1.0f / (float)nG;
    const float invy = 1.0f / (float)nP;
    reduce_kernel<<<256, BLOCK, 0, stream>>>(kmaxX, gts, nG, kmaxY, preds, nP,
                                             invx, invy, out);
}

// Round 4
// 101.681 us; speedup vs baseline: 2.2370x; 2.2370x over previous
//
#include <hip/hip_runtime.h>
#include <hip/hip_bf16.h>
#include <math.h>

// Chamfer distance via single K-packed MFMA per tile, B=8, N=M=8192, D=3, fp32.
//   C[m][n] = q_m.r_n - 0.5*||r_n||^2 via ONE v_mfma_f32_32x32x16_bf16:
//     k0-3 : (qxh,qyh,qzh,1) . (rxh,ryh,rzh,wh)
//     k4-7 : (qxl,qyl,qzl,0) . (rxh,ryh,rzh,wh)
//     k8-11: (qxh,qyh,qzh,1) . (rxl,ryl,rzl,wl)    (w = -0.5*||r||^2, hi/lo bf16)
//   min_j d2 = -2*(w_q_hi + w_q_lo + max_n C), clamped at 0.
// B fragments are stored load-ready by prep (lanes<32 read {hi,hi}, lanes>=32
// read {lo,0}); accumulators forced into arch VGPRs via inline asm; explicit
// s_nop fence covers the MFMA->VALU read hazard that inline asm bypasses.

#define BLOCK 128     // 2 waves
#define WAVES 2
#define QPW 64        // queries per wave: two 32-row MFMA groups

typedef short short8 __attribute__((ext_vector_type(8)));
typedef float f32x16 __attribute__((ext_vector_type(16)));

union U16S { uint4 v; short8 s; };

__device__ __forceinline__ unsigned int bf16hi(float f) {
    __hip_bfloat16 h = __float2bfloat16(f);
    return (unsigned int)*reinterpret_cast<unsigned short*>(&h);
}
__device__ __forceinline__ float bf16f(unsigned int u) {
    unsigned short us = (unsigned short)u;
    __hip_bfloat16 h;
    *reinterpret_cast<unsigned short*>(&h) = us;
    return __bfloat162float(h);
}

__device__ __forceinline__ f32x16 mfma_bf16(short8 a, short8 b, f32x16 c) {
    f32x16 d;
    asm volatile("v_mfma_f32_32x32x16_bf16 %0, %1, %2, %3"
                 : "=v"(d) : "v"(a), "v"(b), "v"(c));
    return d;
}
// 16+ cycles of wait states between MFMA issue and VALU reads of the dests;
// data-tied so the scheduler cannot move the folds above it.
__device__ __forceinline__ void mfma_fence(f32x16& a, f32x16& b, f32x16& c, f32x16& d) {
    asm volatile("s_nop 7\n\ts_nop 7" : "+v"(a), "+v"(b), "+v"(c), "+v"(d));
}

// Per point, two load-ready B-fragment words (32 B):
//   rec[0] = {xh|yh, zh|wh, xh|yh, zh|wh}   (lanes<32: k0-7 = hi,hi)
//   rec[1] = {xl|yl, zl|wl, 0,     0    }   (lanes>=32: k8-15 = lo,0)
__global__ void prep_kernel(const float* __restrict__ gts, const float* __restrict__ preds,
                            int nG, int nP, uint4* __restrict__ RBg, uint4* __restrict__ RBp) {
    const int idx = blockIdx.x * blockDim.x + threadIdx.x;
    if (idx >= nG + nP) return;
    const float* src;
    uint4* dst;
    if (idx < nG) { src = gts + 3 * (size_t)idx;          dst = RBg + 2 * (size_t)idx; }
    else          { src = preds + 3 * (size_t)(idx - nG); dst = RBp + 2 * (size_t)(idx - nG); }
    const float x = src[0], y = src[1], z = src[2];
    const float w = -0.5f * (x * x + y * y + z * z);
    const unsigned int xh = bf16hi(x), yh = bf16hi(y), zh = bf16hi(z), wh = bf16hi(w);
    const unsigned int xl = bf16hi(x - bf16f(xh));
    const unsigned int yl = bf16hi(y - bf16f(yh));
    const unsigned int zl = bf16hi(z - bf16f(zh));
    const unsigned int wl = bf16hi(w - bf16f(wh));
    const unsigned int hx = xh | (yh << 16), hzw = zh | (wh << 16);
    const unsigned int lx = xl | (yl << 16), lzw = zl | (wl << 16);
    dst[0] = make_uint4(hx, hzw, hx, hzw);
    dst[1] = make_uint4(lx, lzw, 0u, 0u);
}

__global__ void __launch_bounds__(BLOCK)
nn_kernel(const uint4* __restrict__ RBg, const uint4* __restrict__ RBp,
          float* __restrict__ partials, int N, int M, int B,
          float invx, float invy) {
    const int z = blockIdx.z;
    const bool dirX = (z < B);
    const int b = dirX ? z : z - B;
    const int NQ = dirX ? N : M;
    const int NR = dirX ? M : N;
    const uint4* Qrb = (dirX ? RBg : RBp) + (size_t)b * NQ * 2;
    const uint4* Rrb = (dirX ? RBp : RBg) + (size_t)b * NR * 2;
    const float inv = dirX ? invx : invy;

    const int tid = threadIdx.x;
    const int lane = tid & 63;
    const int wave = tid >> 6;
    const int m = lane & 31;
    const bool hiK = (lane >= 32);        // this half holds k=8..15
    const int qBase = (blockIdx.x * WAVES + wave) * QPW;

    __shared__ float sK[WAVES][QPW];
    __shared__ float sPart[WAVES];

    // ---- A fragments for query groups 0 (rows qBase+0..31) and 1 (+32)
    short8 A0s, A1s;
    float wsum0, wsum1;
    {
        const uint4 h0 = Qrb[(size_t)(qBase + m) * 2];
        const uint4 l0 = Qrb[(size_t)(qBase + m) * 2 + 1];
        const uint4 h1 = Qrb[(size_t)(qBase + 32 + m) * 2];
        const uint4 l1 = Qrb[(size_t)(qBase + 32 + m) * 2 + 1];
        U16S a;
        a.v.x = h0.x;                                   // (qxh, qyh)
        a.v.y = (h0.y & 0xFFFFu) | 0x3F800000u;         // (qzh, 1.0bf16)
        a.v.z = hiK ? 0u : l0.x;                        // (qxl, qyl) | 0
        a.v.w = hiK ? 0u : (l0.y & 0xFFFFu);            // (qzl, 0)   | 0
        A0s = a.s;
        a.v.x = h1.x;
        a.v.y = (h1.y & 0xFFFFu) | 0x3F800000u;
        a.v.z = hiK ? 0u : l1.x;
        a.v.w = hiK ? 0u : (l1.y & 0xFFFFu);
        A1s = a.s;
        wsum0 = bf16f(h0.y >> 16) + bf16f(l0.y >> 16);  // w_q hi+lo (= -0.5||q||^2)
        wsum1 = bf16f(h1.y >> 16) + bf16f(l1.y >> 16);
    }

    f32x16 zc;
    #pragma unroll
    for (int r = 0; r < 16; ++r) zc[r] = 0.0f;
    f32x16 k0, k1;
    #pragma unroll
    for (int r = 0; r < 16; ++r) { k0[r] = -INFINITY; k1[r] = -INFINITY; }

    // B stream: per ref point 2 uint4; this lane reads variant (hiK?1:0).
    const uint4* rp = Rrb + (size_t)m * 2 + (hiK ? 1 : 0);

    auto computeSet = [&](uint4 ta, uint4 tb) {
        U16S ua, ub;
        ua.v = ta; ub.v = tb;
        f32x16 c0 = mfma_bf16(A0s, ua.s, zc);
        f32x16 c1 = mfma_bf16(A1s, ua.s, zc);
        f32x16 c2 = mfma_bf16(A0s, ub.s, zc);
        f32x16 c3 = mfma_bf16(A1s, ub.s, zc);
        mfma_fence(c0, c1, c2, c3);
        #pragma unroll
        for (int r = 0; r < 16; ++r) {
            k0[r] = fmaxf(fmaxf(c0[r], c2[r]), k0[r]);   // v_max3
            k1[r] = fmaxf(fmaxf(c1[r], c3[r]), k1[r]);
        }
    };

    // macro = 4 tiles (128 pts = 256 uint4); unroll-2 alternating reg sets.
    const int nMacro = NR / 128;
    const uint4* p = rp;
    uint4 r0 = p[0], r1 = p[64], r2 = p[128], r3 = p[192];
    uint4 n0, n1, n2, n3;
    for (int i = 0; i < nMacro; i += 2) {
        const uint4* pn = p + 256;
        n0 = pn[0]; n1 = pn[64]; n2 = pn[128]; n3 = pn[192];
        computeSet(r0, r1);
        computeSet(r2, r3);
        const uint4* pn2 = (i + 2 < nMacro) ? (p + 512) : rp;
        r0 = pn2[0]; r1 = pn2[64]; r2 = pn2[128]; r3 = pn2[192];
        computeSet(n0, n1);
        computeSet(n2, n3);
        p += 512;
    }

    // ---- epilogue: cross-lane max within 32-col halves, rows -> LDS
    #pragma unroll
    for (int r = 0; r < 16; ++r) {
        float v0 = k0[r], v1 = k1[r];
        #pragma unroll
        for (int off = 16; off; off >>= 1) {
            v0 = fmaxf(v0, __shfl_xor(v0, off));
            v1 = fmaxf(v1, __shfl_xor(v1, off));
        }
        if (m == 0) {   // lanes 0 and 32
            const int row = (r & 3) + 8 * (r >> 2) + 4 * (lane >> 5);
            sK[wave][row] = v0;
            sK[wave][32 + row] = v1;
        }
    }
    // wave-local LDS round-trip (compiler inserts lgkmcnt wait)
    const float km = sK[wave][lane];
    const float wsum = hiK ? wsum1 : wsum0;
    const float d2 = fmaxf(-2.0f * (wsum + km), 0.0f);
    float contrib = d2 * inv;
    #pragma unroll
    for (int off = 32; off; off >>= 1) contrib += __shfl_xor(contrib, off);
    if (lane == 0) sPart[wave] = contrib;
    __syncthreads();
    if (tid == 0) {
        float s = 0.0f;
        #pragma unroll
        for (int w = 0; w < WAVES; ++w) s += sPart[w];
        partials[blockIdx.z * gridDim.x + blockIdx.x] = s;
    }
}

__global__ void __launch_bounds__(256)
final_kernel(const float* __restrict__ partials, int n, float* __restrict__ out) {
    float s = 0.0f;
    for (int i = threadIdx.x; i < n; i += 256) s += partials[i];
    #pragma unroll
    for (int off = 32; off; off >>= 1) s += __shfl_xor(s, off);
    __shared__ float ws[4];
    if ((threadIdx.x & 63) == 0) ws[threadIdx.x >> 6] = s;
    __syncthreads();
    if (threadIdx.x == 0) out[0] = ws[0] + ws[1] + ws[2] + ws[3];
}

extern "C" void kernel_launch(void* const* d_in, const int* in_sizes, int n_in,
                              void* d_out, int out_size, void* d_ws, size_t ws_size,
                              hipStream_t stream) {
    const float* gts   = (const float*)d_in[0];   // [B, N, 3]
    const float* preds = (const float*)d_in[1];   // [B, M, 3]
    float* out = (float*)d_out;

    const int B = 8;
    const int N = in_sizes[0] / (B * 3);
    const int M = in_sizes[1] / (B * 3);
    const int nG = B * N, nP = B * M;

    uint4* RBg = (uint4*)d_ws;                    // nG*2 uint4
    uint4* RBp = RBg + (size_t)nG * 2;            // nP*2 uint4
    float* partials = (float*)(RBp + (size_t)nP * 2);

    prep_kernel<<<(nG + nP + 255) / 256, 256, 0, stream>>>(gts, preds, nG, nP, RBg, RBp);

    const int gx = N / (WAVES * QPW);             // 64  (N == M for this problem)
    dim3 grid(gx, 1, 2 * B);
    nn_kernel<<<grid, BLOCK, 0, stream>>>(RBg, RBp, partials, N, M, B,
                                          1.0f / (float)nG, 1.0f / (float)nP);

    final_kernel<<<1, 256, 0, stream>>>(partials, 2 * B * gx, out);
}